// Round 12
// baseline (45.241 us; speedup 1.0000x reference)
//
#include <hip/hip_runtime.h>
#include <math.h>

typedef float v2f __attribute__((ext_vector_type(2)));

#define HALF 64
#define DFE  128
#define B    4096          // HALF*HALF
#define NF   8192          // 2*B
#define GRAM_BLOCKS  256   // full chip: 1 block/CU, 32 outputs each
#define SAME_BLOCKS  1024  // 8 rows each (both halves)
#define CROSS_BLOCKS 1024  // 4 src rows each x full trgt half
#define PAIR_BLOCKS  (SAME_BLOCKS + CROSS_BLOCKS)
#define LOG2E 1.4426950408889634074
#define XP   130           // padded j-row stride (2 mod 32 -> <=4-way banks)

// R12 = R11 EXACTLY, but pair_kernel launched 3x (instances 2,3 -> scratch).
// Purpose: measure k_pair = (T_R12 - T_R11)/2 - g. Two consecutive failed
// predictions (R10 kern_b4 null, R11 gram-parallelize null) mean the cost
// model is wrong; rocprof top-5 is clogged by 38us harness poison fills.

// K(u)=u+u^2+u^4+u^8+u^16, u=2^{-(d*d)}; d pre-scaled by sqrt(log2e/(4*Dm)).
// d=1e18 sentinel => exp2(-1e36)=0 exactly => pair contributes 0.
__device__ __forceinline__ void kern_d(v2f d, v2f& a1, v2f& a2, v2f& a3) {
    const v2f m = d * d;
    v2f u;
    u.x = __builtin_amdgcn_exp2f(-m.x);
    u.y = __builtin_amdgcn_exp2f(-m.y);
    const v2f u2 = u * u;
    const v2f u4 = u2 * u2;
    const v2f u8 = u4 * u4;
    a1 += u + u2;
    a2 += u4 + u8;
    a3 += u8 * u8;     // + u^16
}

// 4 v2f (8 pairs) per call: independent exp chains for ILP.
__device__ __forceinline__ void kern_b4(v2f d0, v2f d1, v2f d2, v2f d3,
                                        v2f& a1, v2f& a2, v2f& a3) {
    const v2f m0 = d0 * d0, m1 = d1 * d1, m2 = d2 * d2, m3 = d3 * d3;
    v2f u0, u1, u2, u3;
    u0.x = __builtin_amdgcn_exp2f(-m0.x); u0.y = __builtin_amdgcn_exp2f(-m0.y);
    u1.x = __builtin_amdgcn_exp2f(-m1.x); u1.y = __builtin_amdgcn_exp2f(-m1.y);
    u2.x = __builtin_amdgcn_exp2f(-m2.x); u2.y = __builtin_amdgcn_exp2f(-m2.y);
    u3.x = __builtin_amdgcn_exp2f(-m3.x); u3.y = __builtin_amdgcn_exp2f(-m3.y);
    const v2f q0 = u0 * u0, q1 = u1 * u1, q2 = u2 * u2, q3 = u3 * u3;   // u^2
    const v2f r0 = q0 * q0, r1 = q1 * q1, r2 = q2 * q2, r3 = q3 * q3;   // u^4
    const v2f w0 = r0 * r0, w1 = r1 * r1, w2 = r2 * r2, w3 = r3 * r3;   // u^8
    a1 += ((u0 + q0) + (u1 + q1)) + ((u2 + q2) + (u3 + q3));
    a2 += ((r0 + w0) + (r1 + w1)) + ((r2 + w2) + (r3 + w3));
    a3 += ((w0 * w0) + (w1 * w1)) + ((w2 * w2) + (w3 * w3));            // u^16
}

// ---------------- K1: cosine Gram, full-chip (256 blocks x 32 outputs) -----
__global__ __launch_bounds__(256) void gram_kernel(const float* __restrict__ feats,
                                                   float* __restrict__ ff,
                                                   double* __restrict__ pm) {
    __shared__ float  xi[DFE];          // row i
    __shared__ float  xj[32 * XP];      // 32 j-rows, padded
    __shared__ double invs[33];         // inv_j[0..31], inv_i at [32]
    __shared__ double wred[8];
    const int tid = threadIdx.x;
    const int b   = blockIdx.x;
    const int h   = b >> 7;
    const int seg = b & 127;
    const int i   = seg >> 1;
    const int jb  = (seg & 1) << 5;
    const float* fh = feats + h * HALF * DFE;

    // stage 32 j-rows (1024 float4s, 4 per thread)
    #pragma unroll
    for (int t = 0; t < 4; ++t) {
        const int idx = tid + 256 * t;
        const int r = idx >> 5, c = (idx & 31) << 2;
        const float4 v = *(const float4*)(fh + (jb + r) * DFE + c);
        *(float2*)&xj[r * XP + c]     = make_float2(v.x, v.y);
        *(float2*)&xj[r * XP + c + 2] = make_float2(v.z, v.w);
    }
    if (tid < 32)   // stage row i
        *(float4*)&xi[tid << 2] = *(const float4*)(fh + i * DFE + (tid << 2));
    __syncthreads();

    // norms: 4 threads per row, 33 rows (row 32 = row i)
    if (tid < 132) {
        const int r = tid >> 2, q = tid & 3;
        const float* row = (r < 32) ? &xj[r * XP + (q << 5)] : &xi[q << 5];
        double s0 = 0.0, s1 = 0.0;
        #pragma unroll
        for (int k = 0; k < 32; k += 2) {
            const float2 v = *(const float2*)&row[k];
            s0 = fma((double)v.x, (double)v.x, s0);
            s1 = fma((double)v.y, (double)v.y, s1);
        }
        double s = s0 + s1;
        s += __shfl_xor(s, 1);
        s += __shfl_xor(s, 2);
        if (q == 0) invs[r] = 1.0 / fmax(sqrt(s), 1e-8);
    }
    __syncthreads();

    // dots: 8 threads per output (16 f64 fma each), shuffle reduce
    const int o = tid >> 3, part = tid & 7;
    const float* rj = &xj[o * XP + (part << 4)];
    const float* ri = &xi[part << 4];
    double s0 = 0.0, s1 = 0.0;
    #pragma unroll
    for (int k = 0; k < 16; k += 2) {
        const float2 a = *(const float2*)&ri[k];
        const float2 c = *(const float2*)&rj[k];
        s0 = fma((double)a.x, (double)c.x, s0);
        s1 = fma((double)a.y, (double)c.y, s1);
    }
    double s = s0 + s1;
    s += __shfl_xor(s, 1);
    s += __shfl_xor(s, 2);
    s += __shfl_xor(s, 4);
    double v = 0.0;
    if (part == 0) {
        v = s * invs[32] * invs[o];
        ff[h * B + i * 64 + jb + o] = (float)v;   // row-major Gram, f32
    }

    // moments (f64): butterfly (v=0 on non-lead lanes), 4 wave-partials
    double r1 = v, r2 = v * v;
    #pragma unroll
    for (int msk = 1; msk < 64; msk <<= 1) {
        r1 += __shfl_xor(r1, msk);
        r2 += __shfl_xor(r2, msk);
    }
    if ((tid & 63) == 0) { wred[(tid >> 6) * 2] = r1; wred[(tid >> 6) * 2 + 1] = r2; }
    __syncthreads();
    if (tid == 0) {
        pm[2 * b]     = (wred[0] + wred[2]) + (wred[4] + wred[6]);
        pm[2 * b + 1] = (wred[1] + wred[3]) + (wred[5] + wred[7]);
    }
}

// ---------------- K2: pair sums, 2048 uniform blocks -----------------------
// [identical to R11 — coverage verified R8]
__global__ __launch_bounds__(256, 8) void pair_kernel(const float* __restrict__ ff,
                                                      const double* __restrict__ pm,
                                                      double* __restrict__ partials) {
    __shared__ float  fs[B];       // 16 KB raw half
    __shared__ float  sclS;
    __shared__ double wred[4];
    const int tid = threadIdx.x;
    const int bid = blockIdx.x;
    const bool same = bid < SAME_BLOCKS;
    const int  r0g  = same ? (bid << 3) : 0;
    const float* src = same ? (ff + (r0g & 4096)) : (ff + B);

    {   // stage 16 KB (raw, scale applied at fragment load)
        const float4* s4 = (const float4*)src;
        float4* d4 = (float4*)fs;
        #pragma unroll
        for (int k = 0; k < 4; ++k) d4[tid + 256 * k] = s4[tid + 256 * k];
    }
    if (tid < 64) {   // wave 0: scl from 512 gram moments, hidden under staging
        double s = 0.0;
        #pragma unroll
        for (int k = 0; k < 8; ++k) s += pm[tid + (k << 6)];   // parity-preserving
        #pragma unroll
        for (int msk = 2; msk <= 32; msk <<= 1) s += __shfl_xor(s, msk);
        const double o = __shfl_xor(s, 1);     // lane0: s=sum, o=sumsq
        if (tid == 0) {
            const double m1 = s * (1.0 / NF);
            const double m2 = o * (1.0 / NF);
            const double Dm = 2.0 * (m2 - m1 * m1);
            sclS = (float)sqrt(LOG2E / (4.0 * Dm));
        }
    }
    __syncthreads();
    const float scl = sclS;

    v2f a1 = {0.f,0.f}, a2 = {0.f,0.f}, a3 = {0.f,0.f};
    v2f n1 = {0.f,0.f}, n2 = {0.f,0.f}, n3 = {0.f,0.f};

    if (same) {
        const int r0l = r0g & 4095;            // multiple of 8
        v2f fi[4];                             // 8 rows, pre-scaled
        #pragma unroll
        for (int q = 0; q < 4; ++q) {
            fi[q].x = fs[r0l + 2 * q]     * scl;
            fi[q].y = fs[r0l + 2 * q + 1] * scl;
        }
        const int c0 = 8 + (tid << 3);         // 8 c-values, c in [8,2055]
        const int j0 = (r0l + c0) & 4095;      // 8-aligned -> aligned b128
        float vj[8], vjs[8];
        *(float4*)&vj[0] = *(const float4*)&fs[j0];
        *(float4*)&vj[4] = *(const float4*)&fs[j0 + 4];
        #pragma unroll
        for (int e = 0; e < 8; ++e) vjs[e] = vj[e] * scl;
        #pragma unroll
        for (int e = 0; e < 8; ++e) {          // fully uniform main loop
            v2f vv; vv.x = vjs[e]; vv.y = vjs[e];
            kern_b4(fi[0] - vv, fi[1] - vv, fi[2] - vv, fi[3] - vv, a1, a2, a3);
        }
        if (tid < 18) {
            // subtract the 36 over-counted pairs: c=2048+m (m<8), rho<=m
            v2f d;
            #pragma unroll
            for (int hp = 0; hp < 2; ++hp) {
                const int idx = 2 * tid + hp;              // [0,36)
                const int m   = (int)((sqrtf((float)(8 * idx + 1)) - 1.0f) * 0.5f);
                const int rho = idx - ((m * (m + 1)) >> 1);
                const float dv = (fs[r0l + rho] - fs[(r0l + 2048 + m) & 4095]) * scl;
                if (hp == 0) d.x = dv; else d.y = dv;
            }
            kern_d(d, n1, n2, n3);
            // add: 28 intra-block triangle (g in [1,7-rho]) + 8 straddle g=2048
            v2f d2;
            #pragma unroll
            for (int hp = 0; hp < 2; ++hp) {
                const int idx = 2 * tid + hp;              // [0,36)
                float dv;
                if (idx < 28) {
                    const int m   = (int)((1.0f + sqrtf((float)(1 + 8 * idx))) * 0.5f);
                    const int g   = idx - ((m * (m - 1)) >> 1) + 1;
                    const int rho = m - g;
                    dv = (fs[r0l + rho] - fs[r0l + rho + g]) * scl;
                } else {
                    const int rho = idx - 28;
                    dv = (r0l < 2048)
                       ? (fs[r0l + rho] - fs[r0l + rho + 2048]) * scl : 1e18f;
                }
                if (hp == 0) d2.x = dv; else d2.y = dv;
            }
            kern_d(d2, a1, a2, a3);
        }
    } else {
        const int r0c = (bid - SAME_BLOCKS) << 2;  // 4 src rows
        v2f fi[2];
        #pragma unroll
        for (int q = 0; q < 2; ++q) {
            fi[q].x = ff[r0c + 2 * q]     * scl;
            fi[q].y = ff[r0c + 2 * q + 1] * scl;
        }
        const int c0 = tid << 4;               // 16 contiguous trgt values
        float vj[16], vjs[16];
        #pragma unroll
        for (int k = 0; k < 4; ++k)
            *(float4*)&vj[4 * k] = *(const float4*)&fs[c0 + 4 * k];
        #pragma unroll
        for (int e = 0; e < 16; ++e) vjs[e] = vj[e] * scl;
        #pragma unroll
        for (int e = 0; e < 16; e += 2) {      // 2 e's x 2 rows = batch of 4
            v2f v0, v1;
            v0.x = vjs[e];     v0.y = vjs[e];
            v1.x = vjs[e + 1]; v1.y = vjs[e + 1];
            kern_b4(fi[0] - v0, fi[1] - v0, fi[0] - v1, fi[1] - v1, a1, a2, a3);
        }
    }

    // block reduce: f64 convert, in-wave butterfly, 4 wave-partials via LDS
    double t = (((double)a1.x + (double)a1.y) + ((double)a2.x + (double)a2.y)
             +  ((double)a3.x + (double)a3.y))
             - (((double)n1.x + (double)n1.y) + ((double)n2.x + (double)n2.y)
             +  ((double)n3.x + (double)n3.y));
    #pragma unroll
    for (int msk = 1; msk < 64; msk <<= 1) t += __shfl_xor(t, msk);
    if ((tid & 63) == 0) wred[tid >> 6] = t;
    __syncthreads();
    if (tid == 0) partials[bid] = (wred[0] + wred[1]) + (wred[2] + wred[3]);
}

// ---------------- K3: deterministic final reduce + loss --------------------
__global__ __launch_bounds__(256) void final_kernel(const double* __restrict__ partials,
                                                    float* __restrict__ out) {
    __shared__ double rs[256], rc[256];
    const int tid = threadIdx.x;
    double a = 0.0, b = 0.0;
    for (int i = tid; i < SAME_BLOCKS; i += 256)  a += partials[i];
    for (int i = tid; i < CROSS_BLOCKS; i += 256) b += partials[SAME_BLOCKS + i];
    rs[tid] = a; rc[tid] = b;
    __syncthreads();
    for (int off = 128; off > 0; off >>= 1) {
        if (tid < off) { rs[tid] += rs[tid + off]; rc[tid] += rc[tid + off]; }
        __syncthreads();
    }
    if (tid == 0) {
        const double S_same  = 2.0 * rs[0];   // unordered -> ordered
        const double S_cross = 2.0 * rc[0];   // one direction -> both
        const double bb = (double)B;
        const double loss = S_same / (bb * (bb - 1.0))
                          - S_cross / (bb * bb)
                          + 2.0 / (bb - 1.0);
        out[0] = (float)loss;
    }
}

extern "C" void kernel_launch(void* const* d_in, const int* in_sizes, int n_in,
                              void* d_out, int out_size, void* d_ws, size_t ws_size,
                              hipStream_t stream) {
    const float* feats = (const float*)d_in[0];
    float* out = (float*)d_out;
    double* ws = (double*)d_ws;

    double* pm        = ws;                          // 512 doubles
    double* partials  = ws + 512;                    // 2048 doubles (REAL)
    double* partials2 = ws + 512 + 2048;             // 2048 doubles (scratch)
    double* partials3 = ws + 512 + 4096;             // 2048 doubles (scratch)
    float*  ff        = (float*)(ws + 512 + 6144);   // 8192 floats

    gram_kernel <<<GRAM_BLOCKS, 256, 0, stream>>>(feats, ff, pm);
    // INSTRUMENTATION: 3x pair. T = const + 3*k_pair. Instances 2,3 are
    // identical work writing unread scratch -> deterministic, output unchanged.
    pair_kernel <<<PAIR_BLOCKS, 256, 0, stream>>>(ff, pm, partials);
    pair_kernel <<<PAIR_BLOCKS, 256, 0, stream>>>(ff, pm, partials2);
    pair_kernel <<<PAIR_BLOCKS, 256, 0, stream>>>(ff, pm, partials3);
    final_kernel<<<1,           256, 0, stream>>>(partials, out);
}

// Round 13
// 23.721 us; speedup vs baseline: 1.9072x; 1.9072x over previous
//
#include <hip/hip_runtime.h>
#include <math.h>

typedef float v2f __attribute__((ext_vector_type(2)));

#define HALF 64
#define DFE  128
#define B    4096          // HALF*HALF
#define NF   8192          // 2*B
#define GRAM_BLOCKS  256   // full chip: 1 block/CU, 32 outputs each
#define SAME_BLOCKS  1024  // 8 rows each (both halves)
#define CROSS_BLOCKS 1024  // 4 src rows each x full trgt half
#define PAIR_BLOCKS  (SAME_BLOCKS + CROSS_BLOCKS)
#define LOG2E 1.4426950408889634074
#define XP   130           // padded j-row stride (2 mod 32 -> <=4-way banks)

// ISSUE-COST MODEL (R12 measurement): pair = 10.6us incremental. Main loop
// per kern_b4 = 36 pk-VALU(4cyc) + 8 v_exp_f32(8cyc) -> 2944 cyc/wave x 8
// waves/SIMD = 5.6us issue floor; VALU+trans issue ~100% combined. The
// polynomial (5 powers + 1 exp / pair) has no fewer-op form. Remaining
// reducible: per-wave f64 butterfly epilogues -> wave-0-only (this round).

// K(u)=u+u^2+u^4+u^8+u^16, u=2^{-(d*d)}; d pre-scaled by sqrt(log2e/(4*Dm)).
// d=1e18 sentinel => exp2(-1e36)=0 exactly => pair contributes 0.
__device__ __forceinline__ void kern_d(v2f d, v2f& a1, v2f& a2, v2f& a3) {
    const v2f m = d * d;
    v2f u;
    u.x = __builtin_amdgcn_exp2f(-m.x);
    u.y = __builtin_amdgcn_exp2f(-m.y);
    const v2f u2 = u * u;
    const v2f u4 = u2 * u2;
    const v2f u8 = u4 * u4;
    a1 += u + u2;
    a2 += u4 + u8;
    a3 += u8 * u8;     // + u^16
}

// 4 v2f (8 pairs) per call: independent exp chains.
__device__ __forceinline__ void kern_b4(v2f d0, v2f d1, v2f d2, v2f d3,
                                        v2f& a1, v2f& a2, v2f& a3) {
    const v2f m0 = d0 * d0, m1 = d1 * d1, m2 = d2 * d2, m3 = d3 * d3;
    v2f u0, u1, u2, u3;
    u0.x = __builtin_amdgcn_exp2f(-m0.x); u0.y = __builtin_amdgcn_exp2f(-m0.y);
    u1.x = __builtin_amdgcn_exp2f(-m1.x); u1.y = __builtin_amdgcn_exp2f(-m1.y);
    u2.x = __builtin_amdgcn_exp2f(-m2.x); u2.y = __builtin_amdgcn_exp2f(-m2.y);
    u3.x = __builtin_amdgcn_exp2f(-m3.x); u3.y = __builtin_amdgcn_exp2f(-m3.y);
    const v2f q0 = u0 * u0, q1 = u1 * u1, q2 = u2 * u2, q3 = u3 * u3;   // u^2
    const v2f r0 = q0 * q0, r1 = q1 * q1, r2 = q2 * q2, r3 = q3 * q3;   // u^4
    const v2f w0 = r0 * r0, w1 = r1 * r1, w2 = r2 * r2, w3 = r3 * r3;   // u^8
    a1 += ((u0 + q0) + (u1 + q1)) + ((u2 + q2) + (u3 + q3));
    a2 += ((r0 + w0) + (r1 + w1)) + ((r2 + w2) + (r3 + w3));
    a3 += ((w0 * w0) + (w1 * w1)) + ((w2 * w2) + (w3 * w3));            // u^16
}

// ---------------- K1: cosine Gram, full-chip (256 blocks x 32 outputs) -----
__global__ __launch_bounds__(256) void gram_kernel(const float* __restrict__ feats,
                                                   float* __restrict__ ff,
                                                   double* __restrict__ pm) {
    __shared__ float  xi[DFE];          // row i
    __shared__ float  xj[32 * XP];      // 32 j-rows, padded
    __shared__ double invs[33];         // inv_j[0..31], inv_i at [32]
    __shared__ double red1l[256], red2l[256];
    const int tid = threadIdx.x;
    const int b   = blockIdx.x;
    const int h   = b >> 7;
    const int seg = b & 127;
    const int i   = seg >> 1;
    const int jb  = (seg & 1) << 5;
    const float* fh = feats + h * HALF * DFE;

    // stage 32 j-rows (1024 float4s, 4 per thread)
    #pragma unroll
    for (int t = 0; t < 4; ++t) {
        const int idx = tid + 256 * t;
        const int r = idx >> 5, c = (idx & 31) << 2;
        const float4 v = *(const float4*)(fh + (jb + r) * DFE + c);
        *(float2*)&xj[r * XP + c]     = make_float2(v.x, v.y);
        *(float2*)&xj[r * XP + c + 2] = make_float2(v.z, v.w);
    }
    if (tid < 32)   // stage row i
        *(float4*)&xi[tid << 2] = *(const float4*)(fh + i * DFE + (tid << 2));
    __syncthreads();

    // norms: 4 threads per row, 33 rows (row 32 = row i)
    if (tid < 132) {
        const int r = tid >> 2, q = tid & 3;
        const float* row = (r < 32) ? &xj[r * XP + (q << 5)] : &xi[q << 5];
        double s0 = 0.0, s1 = 0.0;
        #pragma unroll
        for (int k = 0; k < 32; k += 2) {
            const float2 v = *(const float2*)&row[k];
            s0 = fma((double)v.x, (double)v.x, s0);
            s1 = fma((double)v.y, (double)v.y, s1);
        }
        double s = s0 + s1;
        s += __shfl_xor(s, 1);
        s += __shfl_xor(s, 2);
        if (q == 0) invs[r] = 1.0 / fmax(sqrt(s), 1e-8);
    }
    __syncthreads();

    // dots: 8 threads per output (16 f64 fma each), shuffle reduce
    const int o = tid >> 3, part = tid & 7;
    const float* rj = &xj[o * XP + (part << 4)];
    const float* ri = &xi[part << 4];
    double s0 = 0.0, s1 = 0.0;
    #pragma unroll
    for (int k = 0; k < 16; k += 2) {
        const float2 a = *(const float2*)&ri[k];
        const float2 c = *(const float2*)&rj[k];
        s0 = fma((double)a.x, (double)c.x, s0);
        s1 = fma((double)a.y, (double)c.y, s1);
    }
    double s = s0 + s1;
    s += __shfl_xor(s, 1);
    s += __shfl_xor(s, 2);
    s += __shfl_xor(s, 4);
    double v = 0.0;
    if (part == 0) {
        v = s * invs[32] * invs[o];
        ff[h * B + i * 64 + jb + o] = (float)v;   // row-major Gram, f32
    }

    // moments (f64): stash to LDS, wave 0 alone reduces (fixed order)
    red1l[tid] = v; red2l[tid] = v * v;
    __syncthreads();
    if (tid < 64) {
        double r1 = (red1l[tid] + red1l[tid + 64]) + (red1l[tid + 128] + red1l[tid + 192]);
        double r2 = (red2l[tid] + red2l[tid + 64]) + (red2l[tid + 128] + red2l[tid + 192]);
        #pragma unroll
        for (int msk = 1; msk < 64; msk <<= 1) {
            r1 += __shfl_xor(r1, msk);
            r2 += __shfl_xor(r2, msk);
        }
        if (tid == 0) { pm[2 * b] = r1; pm[2 * b + 1] = r2; }
    }
}

// ---------------- K2: pair sums, 2048 uniform blocks -----------------------
// Same blocks (bid<1024): 8 rows in VGPRs, uniform window c in [8,2055]
//   (NO predication in main loop); 36 over-counted g>=2048 pairs recomputed
//   into negative accumulators; edge adds g in [1,7-rho] (28) + straddle
//   g=2048 (8, first-half blocks only).       [coverage verified R8]
// Cross blocks: 4 src rows x full trgt half.
// NOTE (R5/R9 lessons): NO cross-block fusion of the final reduce.
__global__ __launch_bounds__(256, 8) void pair_kernel(const float* __restrict__ ff,
                                                      const double* __restrict__ pm,
                                                      double* __restrict__ partials) {
    __shared__ float  fs[B];       // 16 KB raw half
    __shared__ float  sclS;
    __shared__ double redl[256];   // 2 KB epilogue stash
    const int tid = threadIdx.x;
    const int bid = blockIdx.x;
    const bool same = bid < SAME_BLOCKS;
    const int  r0g  = same ? (bid << 3) : 0;
    const float* src = same ? (ff + (r0g & 4096)) : (ff + B);

    {   // stage 16 KB (raw, scale applied at fragment load)
        const float4* s4 = (const float4*)src;
        float4* d4 = (float4*)fs;
        #pragma unroll
        for (int k = 0; k < 4; ++k) d4[tid + 256 * k] = s4[tid + 256 * k];
    }
    if (tid < 64) {   // wave 0: scl from 512 gram moments, hidden under staging
        double s = 0.0;
        #pragma unroll
        for (int k = 0; k < 8; ++k) s += pm[tid + (k << 6)];   // parity-preserving
        #pragma unroll
        for (int msk = 2; msk <= 32; msk <<= 1) s += __shfl_xor(s, msk);
        const double o = __shfl_xor(s, 1);     // lane0: s=sum, o=sumsq
        if (tid == 0) {
            const double m1 = s * (1.0 / NF);
            const double m2 = o * (1.0 / NF);
            const double Dm = 2.0 * (m2 - m1 * m1);
            sclS = (float)sqrt(LOG2E / (4.0 * Dm));
        }
    }
    __syncthreads();
    const float scl = sclS;

    v2f a1 = {0.f,0.f}, a2 = {0.f,0.f}, a3 = {0.f,0.f};
    v2f n1 = {0.f,0.f}, n2 = {0.f,0.f}, n3 = {0.f,0.f};

    if (same) {
        const int r0l = r0g & 4095;            // multiple of 8
        v2f fi[4];                             // 8 rows, pre-scaled
        #pragma unroll
        for (int q = 0; q < 4; ++q) {
            fi[q].x = fs[r0l + 2 * q]     * scl;
            fi[q].y = fs[r0l + 2 * q + 1] * scl;
        }
        const int c0 = 8 + (tid << 3);         // 8 c-values, c in [8,2055]
        const int j0 = (r0l + c0) & 4095;      // 8-aligned -> aligned b128
        float vj[8], vjs[8];
        *(float4*)&vj[0] = *(const float4*)&fs[j0];
        *(float4*)&vj[4] = *(const float4*)&fs[j0 + 4];
        #pragma unroll
        for (int e = 0; e < 8; ++e) vjs[e] = vj[e] * scl;
        #pragma unroll
        for (int e = 0; e < 8; ++e) {          // fully uniform main loop
            v2f vv; vv.x = vjs[e]; vv.y = vjs[e];
            kern_b4(fi[0] - vv, fi[1] - vv, fi[2] - vv, fi[3] - vv, a1, a2, a3);
        }
        if (tid < 18) {
            // subtract the 36 over-counted pairs: c=2048+m (m<8), rho<=m
            v2f d;
            #pragma unroll
            for (int hp = 0; hp < 2; ++hp) {
                const int idx = 2 * tid + hp;              // [0,36)
                const int m   = (int)((sqrtf((float)(8 * idx + 1)) - 1.0f) * 0.5f);
                const int rho = idx - ((m * (m + 1)) >> 1);
                const float dv = (fs[r0l + rho] - fs[(r0l + 2048 + m) & 4095]) * scl;
                if (hp == 0) d.x = dv; else d.y = dv;
            }
            kern_d(d, n1, n2, n3);
            // add: 28 intra-block triangle (g in [1,7-rho]) + 8 straddle g=2048
            v2f d2;
            #pragma unroll
            for (int hp = 0; hp < 2; ++hp) {
                const int idx = 2 * tid + hp;              // [0,36)
                float dv;
                if (idx < 28) {
                    const int m   = (int)((1.0f + sqrtf((float)(1 + 8 * idx))) * 0.5f);
                    const int g   = idx - ((m * (m - 1)) >> 1) + 1;
                    const int rho = m - g;
                    dv = (fs[r0l + rho] - fs[r0l + rho + g]) * scl;
                } else {
                    const int rho = idx - 28;
                    dv = (r0l < 2048)
                       ? (fs[r0l + rho] - fs[r0l + rho + 2048]) * scl : 1e18f;
                }
                if (hp == 0) d2.x = dv; else d2.y = dv;
            }
            kern_d(d2, a1, a2, a3);
        }
    } else {
        const int r0c = (bid - SAME_BLOCKS) << 2;  // 4 src rows
        v2f fi[2];
        #pragma unroll
        for (int q = 0; q < 2; ++q) {
            fi[q].x = ff[r0c + 2 * q]     * scl;
            fi[q].y = ff[r0c + 2 * q + 1] * scl;
        }
        const int c0 = tid << 4;               // 16 contiguous trgt values
        float vj[16], vjs[16];
        #pragma unroll
        for (int k = 0; k < 4; ++k)
            *(float4*)&vj[4 * k] = *(const float4*)&fs[c0 + 4 * k];
        #pragma unroll
        for (int e = 0; e < 16; ++e) vjs[e] = vj[e] * scl;
        #pragma unroll
        for (int e = 0; e < 16; e += 2) {      // 2 e's x 2 rows = batch of 4
            v2f v0, v1;
            v0.x = vjs[e];     v0.y = vjs[e];
            v1.x = vjs[e + 1]; v1.y = vjs[e + 1];
            kern_b4(fi[0] - v0, fi[1] - v0, fi[0] - v1, fi[1] - v1, a1, a2, a3);
        }
    }

    // epilogue: f64 total -> LDS stash; wave 0 alone reduces (fixed order).
    // (R12: per-wave butterflies were ~1us chip-wide; this removes 3/4.)
    double t = (((double)a1.x + (double)a1.y) + ((double)a2.x + (double)a2.y)
             +  ((double)a3.x + (double)a3.y))
             - (((double)n1.x + (double)n1.y) + ((double)n2.x + (double)n2.y)
             +  ((double)n3.x + (double)n3.y));
    redl[tid] = t;
    __syncthreads();
    if (tid < 64) {
        double s = (redl[tid] + redl[tid + 64]) + (redl[tid + 128] + redl[tid + 192]);
        #pragma unroll
        for (int msk = 1; msk < 64; msk <<= 1) s += __shfl_xor(s, msk);
        if (tid == 0) partials[bid] = s;
    }
}

// ---------------- K3: deterministic final reduce + loss --------------------
__global__ __launch_bounds__(256) void final_kernel(const double* __restrict__ partials,
                                                    float* __restrict__ out) {
    __shared__ double rs[256], rc[256];
    const int tid = threadIdx.x;
    double a = 0.0, b = 0.0;
    for (int i = tid; i < SAME_BLOCKS; i += 256)  a += partials[i];
    for (int i = tid; i < CROSS_BLOCKS; i += 256) b += partials[SAME_BLOCKS + i];
    rs[tid] = a; rc[tid] = b;
    __syncthreads();
    for (int off = 128; off > 0; off >>= 1) {
        if (tid < off) { rs[tid] += rs[tid + off]; rc[tid] += rc[tid + off]; }
        __syncthreads();
    }
    if (tid == 0) {
        const double S_same  = 2.0 * rs[0];   // unordered -> ordered
        const double S_cross = 2.0 * rc[0];   // one direction -> both
        const double bb = (double)B;
        const double loss = S_same / (bb * (bb - 1.0))
                          - S_cross / (bb * bb)
                          + 2.0 / (bb - 1.0);
        out[0] = (float)loss;
    }
}

extern "C" void kernel_launch(void* const* d_in, const int* in_sizes, int n_in,
                              void* d_out, int out_size, void* d_ws, size_t ws_size,
                              hipStream_t stream) {
    const float* feats = (const float*)d_in[0];
    float* out = (float*)d_out;
    double* ws = (double*)d_ws;

    double* pm       = ws;                          // 512 doubles
    double* partials = ws + 512;                    // 2048 doubles
    float*  ff       = (float*)(ws + 512 + 2048);   // 8192 floats

    gram_kernel <<<GRAM_BLOCKS, 256, 0, stream>>>(feats, ff, pm);
    pair_kernel <<<PAIR_BLOCKS, 256, 0, stream>>>(ff, pm, partials);
    final_kernel<<<1,           256, 0, stream>>>(partials, out);
}